// Round 12
// baseline (2813.084 us; speedup 1.0000x reference)
//
#include <hip/hip_runtime.h>

#define DEVI static __device__ __forceinline__

typedef float    f32x4 __attribute__((ext_vector_type(4)));
typedef _Float16 f16x8 __attribute__((ext_vector_type(8)));

static constexpr int Bn = 8, Ln = 4096, Dn = 1024, Hn = 16, DKn = 64;
static constexpr int TOPK = 8;
static constexpr float LO_SCALE = 2048.f, LO_INV = 1.f / 2048.f;

DEVI f32x4 mfma_f16(f16x8 a, f16x8 b, f32x4 c) {
    return __builtin_amdgcn_mfma_f32_16x16x32_f16(a, b, c, 0, 0, 0);
}

struct HL { _Float16 hi, lo; };
// split f32 -> f16 hi + f16 lo*2048 (prescaled so lo stays in normal f16
// range; MFMA flushes subnormal inputs which would kill the correction)
DEVI HL split2(float x) {
    HL r;
    r.hi = (_Float16)x;
    r.lo = (_Float16)((x - (float)r.hi) * LO_SCALE);
    return r;
}

// async global->LDS, 16B per lane, LDS dest = wave-uniform base + lane*16
DEVI void gload16(const void* g, void* l) {
    __builtin_amdgcn_global_load_lds(
        (const __attribute__((address_space(1))) unsigned int*)g,
        (__attribute__((address_space(3))) unsigned int*)l,
        16, 0, 0);
}

// ---------------------------------------------------------------------------
// dtype conversion kernels (one-time, memory-bound)
// ---------------------------------------------------------------------------
__global__ __launch_bounds__(256) void cvt_split_k(
    const float* __restrict__ srcA, _Float16* __restrict__ hiA, _Float16* __restrict__ loA,
    const float* __restrict__ srcB, _Float16* __restrict__ hiB, _Float16* __restrict__ loB,
    int n8)
{
    const float* s  = blockIdx.y ? srcB : srcA;
    _Float16*    ph = blockIdx.y ? hiB  : hiA;
    _Float16*    pl = blockIdx.y ? loB  : loA;
    const int idx = blockIdx.x * 256 + threadIdx.x;
    if (idx >= n8) return;
    f32x4 x0 = *(const f32x4*)(s + (size_t)idx * 8);
    f32x4 x1 = *(const f32x4*)(s + (size_t)idx * 8 + 4);
    f16x8 h, l;
#pragma unroll
    for (int j = 0; j < 4; j++) {
        HL p0 = split2(x0[j]), p1 = split2(x1[j]);
        h[j] = p0.hi; l[j] = p0.lo;
        h[4 + j] = p1.hi; l[4 + j] = p1.lo;
    }
    *(f16x8*)(ph + (size_t)idx * 8) = h;
    *(f16x8*)(pl + (size_t)idx * 8) = l;
}

__global__ __launch_bounds__(256) void cvt_f16_k(
    const float* __restrict__ srcA, _Float16* __restrict__ dstA,
    const float* __restrict__ srcB, _Float16* __restrict__ dstB, int n8)
{
    const float* s = blockIdx.y ? srcB : srcA;
    _Float16*    d = blockIdx.y ? dstB : dstA;
    const int idx = blockIdx.x * 256 + threadIdx.x;
    if (idx >= n8) return;
    f32x4 x0 = *(const f32x4*)(s + (size_t)idx * 8);
    f32x4 x1 = *(const f32x4*)(s + (size_t)idx * 8 + 4);
    f16x8 o;
#pragma unroll
    for (int j = 0; j < 4; j++) { o[j] = (_Float16)x0[j]; o[4 + j] = (_Float16)x1[j]; }
    *(f16x8*)(d + (size_t)idx * 8) = o;
}

// ---------------------------------------------------------------------------
// m97-structure GEMM: C[m,n] = sum_k A[m,k]*W[n,k] + bias[n], K = 1024.
// 128x128 tile, BK=32, 4 waves, global_load_lds staging, 2-barrier K-loop.
// COMP: A/W have hi+scaled-lo pairs; 3-term compensated MFMA (f32-accurate).
// ---------------------------------------------------------------------------
DEVI void stage8(const _Float16* gbase, _Float16* ltile, int w, int lane, int k0) {
#pragma unroll
    for (int c = 0; c < 2; c++) {
        const int chunk = 2 * w + c;
        const int row = chunk * 16 + (lane >> 2);
        gload16(gbase + (size_t)row * Dn + k0 + (lane & 3) * 8, ltile + chunk * 512);
    }
}

template<int MODE, bool COMP>
DEVI void gemm2_body(
    const _Float16* __restrict__ A_hi, const _Float16* __restrict__ A_lo,
    const _Float16* __restrict__ W_hi, const _Float16* __restrict__ W_lo,
    const float* __restrict__ bias, void* __restrict__ out0, void* __restrict__ out1)
{
    __shared__ _Float16 lds[(COMP ? 4 : 2) * 4096];
    _Float16* sAh = lds;
    _Float16* sWh = lds + 4096;
    _Float16* sAl = COMP ? lds + 8192  : lds;
    _Float16* sWl = COMP ? lds + 12288 : lds;

    const int l  = threadIdx.x & 63;
    const int w  = threadIdx.x >> 6;
    const int m0 = blockIdx.x * 128;
    const int n0 = blockIdx.y * 128;
    const int wm = (w & 1) * 64, wn = (w >> 1) * 64;
    const int rr = l & 15, ko = (l >> 4) * 8;

    const _Float16* Abh = A_hi + (size_t)m0 * Dn;
    const _Float16* Wbh = W_hi + (size_t)n0 * Dn;
    const _Float16* Abl = COMP ? A_lo + (size_t)m0 * Dn : nullptr;
    const _Float16* Wbl = COMP ? W_lo + (size_t)n0 * Dn : nullptr;

    f32x4 acc[4][4] = {};
    f32x4 accc[4][4] = {};

    for (int k0 = 0; k0 < Dn; k0 += 32) {
        stage8(Abh, sAh, w, l, k0);
        stage8(Wbh, sWh, w, l, k0);
        if (COMP) {
            stage8(Abl, sAl, w, l, k0);
            stage8(Wbl, sWl, w, l, k0);
        }
        __syncthreads();

        f16x8 af[4], bf[4], alf[4], blf[4];
#pragma unroll
        for (int i = 0; i < 4; i++) {
            af[i] = *(const f16x8*)&sAh[(wm + 16 * i + rr) * 32 + ko];
            bf[i] = *(const f16x8*)&sWh[(wn + 16 * i + rr) * 32 + ko];
            if (COMP) {
                alf[i] = *(const f16x8*)&sAl[(wm + 16 * i + rr) * 32 + ko];
                blf[i] = *(const f16x8*)&sWl[(wn + 16 * i + rr) * 32 + ko];
            }
        }
#pragma unroll
        for (int i = 0; i < 4; i++)
#pragma unroll
            for (int j = 0; j < 4; j++) {
                acc[i][j] = mfma_f16(af[i], bf[j], acc[i][j]);
                if (COMP) {
                    accc[i][j] = mfma_f16(alf[i], bf[j], accc[i][j]);
                    accc[i][j] = mfma_f16(af[i], blf[j], accc[i][j]);
                }
            }
        __syncthreads();
    }

#pragma unroll
    for (int i = 0; i < 4; i++)
#pragma unroll
        for (int j = 0; j < 4; j++)
#pragma unroll
            for (int r = 0; r < 4; r++) {
                const int m = m0 + wm + 16 * i + (l >> 4) * 4 + r;
                const int n = n0 + wn + 16 * j + (l & 15);
                float v = acc[i][j][r];
                if (COMP) v += accc[i][j][r] * LO_INV;
                v += bias[n];
                if (MODE == 0) {
                    ((float*)out0)[(size_t)m * Dn + n] = v;
                } else if (MODE == 1) {
                    size_t idx = ((size_t)((m >> 12) * Hn + (n >> 6)) * Ln
                                  + (m & (Ln - 1))) * DKn + (n & 63);
                    ((_Float16*)out0)[idx] = (_Float16)v;
                } else {
                    size_t idx = ((size_t)(n >> 6) * Ln + m) * DKn + (n & 63);
                    HL p = split2(v);
                    ((_Float16*)out0)[idx] = p.hi;
                    ((_Float16*)out1)[idx] = p.lo;
                }
            }
}

__global__ __launch_bounds__(256) void gemm_v_k(
    const _Float16* __restrict__ xv, const _Float16* __restrict__ Wv,
    const float* __restrict__ bv, _Float16* __restrict__ Vstage)
{
    gemm2_body<1, false>(xv, nullptr, Wv, nullptr, bv, Vstage, nullptr);
}

__global__ __launch_bounds__(256) void gemm_o_k(
    const _Float16* __restrict__ Y, const _Float16* __restrict__ Wo,
    const float* __restrict__ bo, float* __restrict__ out)
{
    gemm2_body<0, false>(Y, nullptr, Wo, nullptr, bo, out, nullptr);
}

__global__ __launch_bounds__(256) void gemm_qk_k(
    const _Float16* __restrict__ xqhi, const _Float16* __restrict__ xqlo,
    const _Float16* __restrict__ xkhi, const _Float16* __restrict__ xklo,
    const _Float16* __restrict__ Wqhi, const _Float16* __restrict__ Wqlo,
    const _Float16* __restrict__ Wkhi, const _Float16* __restrict__ Wklo,
    const float* __restrict__ bq, const float* __restrict__ bk,
    _Float16* __restrict__ Qhi, _Float16* __restrict__ Qlo,
    _Float16* __restrict__ Khi, _Float16* __restrict__ Klo)
{
    if (blockIdx.z == 0)
        gemm2_body<2, true>(xqhi, xqlo, Wqhi, Wqlo, bq, Qhi, Qlo);
    else
        gemm2_body<2, true>(xkhi, xklo, Wkhi, Wklo, bk, Khi, Klo);
}

// ---------------------------------------------------------------------------
// Correlation v8 (one batch): K ring-of-3 in LDS + Q register prefetch +
// SINGLE barrier per chunk.
// Block = (head h, 64-diag band t0), XCD-swizzled (XCD x hosts heads 2x,2x+1).
// 64 chunks of 64 s-rows. Per chunk c:
//   stage K(c+1) -> slot (c+1)%3   (global_load_lds, swizzled source)
//   load  Q(c+1) -> registers      (per-lane, wave w reads only its rows)
//   compute chunk c: j=0..4 tile positions; K slot = (c + (w-j)>>2) mod 3
//     = c%3 if w>=j else (c%3+2)%3 -- reads slots {c,c-1}%3, stage writes
//     (c+1)%3: disjoint, so NO barrier between stage and compute.
//   __syncthreads()  (drains vmcnt AFTER compute -> staging latency hidden)
// LDS 48.25KB -> 3 blocks/CU. 20 ds_read_b128 + 30 MFMA per wave-chunk.
// ---------------------------------------------------------------------------
__global__ __launch_bounds__(256) void corr_k(
    const _Float16* __restrict__ Qhi, const _Float16* __restrict__ Qlo,
    const _Float16* __restrict__ Khi, const _Float16* __restrict__ Klo,
    float* __restrict__ corr /* [16][4096] of this batch */)
{
    __shared__ _Float16 sK[3][8192];   // [slot][part*4096 + row*64 + col]
    __shared__ float red[64];

    const int P   = blockIdx.x;
    const int idx = P >> 3;
    const int h   = (P & 7) * 2 + (idx >> 6);   // XCD x hosts heads 2x,2x+1
    const int t0  = (idx & 63) * 64;
    const int l   = threadIdx.x & 63;
    const int w   = threadIdx.x >> 6;
    const int rr  = l & 15;
    const int kf  = (l >> 4) * 8;
    const size_t base = (size_t)h * Ln * DKn;
    const _Float16* Qh = Qhi + base;
    const _Float16* Ql = Qlo + base;
    const _Float16* Kh = Khi + base;
    const _Float16* Kl = Klo + base;

    if (threadIdx.x < 64) red[threadIdx.x] = 0.f;

    // staging lane geometry: each gload16 call covers 8 rows x 64 f16.
    const int lr  = l >> 3;            // row within the 8-row call
    const int gsw = (l & 7) ^ lr;      // pre-swizzled source group (involution)

    f32x4 th[5] = {}, tc[5] = {};

    // ---- stage K chunk c into ring slot ----
    auto stageK = [&](int c, int slot) {
#pragma unroll
        for (int cc = 0; cc < 2; cc++) {
            const int Rb = w * 16 + cc * 8;
            const int grow = (c * 64 - t0 + Rb + lr) & (Ln - 1);
            gload16(Kh + (size_t)grow * DKn + gsw * 8, &sK[slot][Rb * 64]);
            gload16(Kl + (size_t)grow * DKn + gsw * 8, &sK[slot][4096 + Rb * 64]);
        }
    };

    // current / next Q fragments (wave w owns si-tile c*4+w: rows c*64+w*16+rr)
    f16x8 cqh0, cqh1, cql0, cql1, nqh0, nqh1, nql0, nql1;
    {
        const int row = (w * 16 + rr) & (Ln - 1);
        const size_t o = (size_t)row * DKn + kf;
        cqh0 = *(const f16x8*)(Qh + o);
        cqh1 = *(const f16x8*)(Qh + o + 32);
        cql0 = *(const f16x8*)(Ql + o);
        cql1 = *(const f16x8*)(Ql + o + 32);
    }
    stageK(-1, 2);   // chunk -1 -> slot (-1 mod 3) = 2
    stageK(0, 0);
    __syncthreads();

    int c3 = 0;   // c % 3
    for (int c = 0; c < 64; c++) {
        const int ns = (c3 == 2) ? 0 : c3 + 1;        // (c+1) % 3
        // stage K(c+1) and prefetch Q(c+1) -- both disjoint from compute(c)
        stageK(c + 1, ns);
        {
            const int row = ((c + 1) * 64 + w * 16 + rr) & (Ln - 1);
            const size_t o = (size_t)row * DKn + kf;
            nqh0 = *(const f16x8*)(Qh + o);
            nqh1 = *(const f16x8*)(Qh + o + 32);
            nql0 = *(const f16x8*)(Ql + o);
            nql1 = *(const f16x8*)(Ql + o + 32);
        }

        // compute chunk c: slots {c%3, (c-1)%3}
        const int sm1 = (c3 == 0) ? 2 : c3 - 1;
#pragma unroll
        for (int j = 0; j <= 4; j++) {
            const _Float16* Ks = &sK[(w >= j) ? c3 : sm1][0];
            const int kr   = ((w - j) & 3) * 16 + rr;
            const int ksw0 = ((kf >> 3) ^ (kr & 7)) * 8;
            const int ksw1 = (((32 + kf) >> 3) ^ (kr & 7)) * 8;
            f16x8 kh0 = *(const f16x8*)&Ks[kr * 64 + ksw0];
            f16x8 kh1 = *(const f16x8*)&Ks[kr * 64 + ksw1];
            f16x8 kl0 = *(const f16x8*)&Ks[4096 + kr * 64 + ksw0];
            f16x8 kl1 = *(const f16x8*)&Ks[4096 + kr * 64 + ksw1];
            th[j] = mfma_f16(cqh0, kh0, th[j]);
            th[j] = mfma_f16(cqh1, kh1, th[j]);
            tc[j] = mfma_f16(cql0, kh0, tc[j]);
            tc[j] = mfma_f16(cqh0, kl0, tc[j]);
            tc[j] = mfma_f16(cql1, kh1, tc[j]);
            tc[j] = mfma_f16(cqh1, kl1, tc[j]);
        }
        __syncthreads();   // drains staging/prefetch AFTER compute (hidden)
        cqh0 = nqh0; cqh1 = nqh1; cql0 = nql0; cql1 = nql1;
        c3 = ns;
    }

#pragma unroll
    for (int r = 0; r < 4; r++) {
        const int d  = (l >> 4) * 4 + r - rr;   // a - b
        const int dl = d & 15;
        const bool pos = d >= 0;
#pragma unroll
        for (int i = 0; i < 4; i++) {
            const float hh = pos ? th[i][r] : th[i + 1][r];
            const float cc = pos ? tc[i][r] : tc[i + 1][r];
            atomicAdd(&red[dl + 16 * i], hh + cc * LO_INV);
        }
    }
    __syncthreads();
    if (threadIdx.x < 64)
        corr[(size_t)h * Ln + t0 + threadIdx.x] = red[threadIdx.x];
}

// ---------------------------------------------------------------------------
// Top-8 + softmax per (b,h) row of corr (raw sums; /64 before softmax).
// ---------------------------------------------------------------------------
__global__ __launch_bounds__(256) void topk_k(
    const float* __restrict__ corr, float* __restrict__ top_w,
    int* __restrict__ top_idx)
{
    __shared__ float vals[Ln];
    __shared__ float rv[256];
    __shared__ int   ri[256];
    __shared__ float sel_v[TOPK];
    __shared__ int   sel_i[TOPK];
    const int bh = blockIdx.x;
    const float* c = corr + (size_t)bh * Ln;
    for (int i = threadIdx.x; i < Ln; i += 256) vals[i] = c[i];
    __syncthreads();

    for (int it = 0; it < TOPK; it++) {
        float bvv = -1e30f; int bi = 0;
        const int base = threadIdx.x * 16;
#pragma unroll
        for (int j = 0; j < 16; j++) {
            float v = vals[base + j];
            if (v > bvv) { bvv = v; bi = base + j; }
        }
        rv[threadIdx.x] = bvv; ri[threadIdx.x] = bi;
        __syncthreads();
        if (threadIdx.x == 0) {
            float gv = rv[0]; int gi = ri[0];
            for (int t = 1; t < 256; t++)
                if (rv[t] > gv) { gv = rv[t]; gi = ri[t]; }
            sel_v[it] = gv; sel_i[it] = gi;
            vals[gi] = -1e30f;
        }
        __syncthreads();
    }
    if (threadIdx.x == 0) {
        float e[TOPK], s = 0.f;
        for (int i = 0; i < TOPK; i++) {
            e[i] = expf((sel_v[i] - sel_v[0]) * (1.f / 64.f));
            s += e[i];
        }
        for (int i = 0; i < TOPK; i++) {
            top_w[bh * TOPK + i]   = e[i] / s;
            top_idx[bh * TOPK + i] = sel_i[i];
        }
    }
}

// ---------------------------------------------------------------------------
// Aggregation: Y[b][t][h*64+d] = sum_i w_i * V[b][h][(t-idx_i)&4095][d]
// ---------------------------------------------------------------------------
__global__ __launch_bounds__(256) void agg_k(
    const _Float16* __restrict__ V /* [B][H][L][64] */,
    const float* __restrict__ top_w, const int* __restrict__ top_idx,
    _Float16* __restrict__ Y /* [B][L][1024] */)
{
    __shared__ float w_s[TOPK];
    __shared__ int   i_s[TOPK];
    const int bh   = blockIdx.y;
    const int b    = bh >> 4, h = bh & 15;
    const int tloc = threadIdx.x >> 2;
    const int c16  = (threadIdx.x & 3) * 16;
    const int t    = blockIdx.x * 64 + tloc;
    if (threadIdx.x < TOPK) {
        w_s[threadIdx.x] = top_w[bh * TOPK + threadIdx.x];
        i_s[threadIdx.x] = top_idx[bh * TOPK + threadIdx.x];
    }
    __syncthreads();

    const _Float16* Vb = V + (size_t)bh * Ln * DKn;
    float acc[16] = {};
#pragma unroll
    for (int i = 0; i < TOPK; i++) {
        const int src = (t - i_s[i]) & (Ln - 1);
        const _Float16* p = Vb + (size_t)src * DKn + c16;
        f16x8 v0 = *(const f16x8*)(p);
        f16x8 v1 = *(const f16x8*)(p + 8);
        const float wgt = w_s[i];
#pragma unroll
        for (int j = 0; j < 8; j++) acc[j]     += wgt * (float)v0[j];
#pragma unroll
        for (int j = 0; j < 8; j++) acc[8 + j] += wgt * (float)v1[j];
    }
    f16x8 o0, o1;
#pragma unroll
    for (int j = 0; j < 8; j++) { o0[j] = (_Float16)acc[j]; o1[j] = (_Float16)acc[8 + j]; }
    const size_t oidx = ((size_t)(b * Ln + t)) * Dn + h * DKn + c16;
    *(f16x8*)(Y + oidx)     = o0;
    *(f16x8*)(Y + oidx + 8) = o1;
}

// ---------------------------------------------------------------------------
extern "C" void kernel_launch(void* const* d_in, const int* in_sizes, int n_in,
                              void* d_out, int out_size, void* d_ws, size_t ws_size,
                              hipStream_t stream)
{
    const float* q  = (const float*)d_in[0];
    const float* kk = (const float*)d_in[1];
    const float* v  = (const float*)d_in[2];
    const float* Wq = (const float*)d_in[3];
    const float* bq = (const float*)d_in[4];
    const float* Wk = (const float*)d_in[5];
    const float* bk = (const float*)d_in[6];
    const float* Wv = (const float*)d_in[7];
    const float* bv = (const float*)d_in[8];
    const float* Wo = (const float*)d_in[9];
    const float* bo = (const float*)d_in[10];
    float* out = (float*)d_out;

    // ws layout: as round 7 (corr single buffer @ 67108864).
    char* ws = (char*)d_ws;
    if (ws_size < 81797120ull) return;
    _Float16* Qhi  = (_Float16*)(ws);
    _Float16* Qlo  = (_Float16*)(ws + 8388608);
    _Float16* Khi  = (_Float16*)(ws + 16777216);
    _Float16* Klo  = (_Float16*)(ws + 25165824);
    _Float16* xqhi = (_Float16*)(ws + 33554432);
    _Float16* xqlo = (_Float16*)(ws + 41943040);
    _Float16* xkhi = (_Float16*)(ws + 50331648);
    _Float16* xklo = (_Float16*)(ws + 58720256);
    _Float16* Y    = (_Float16*)(ws);
    float*    corr = (float*)(ws + 67108864);
    float*    topw = (float*)(ws + 69206016);
    int*      topi = (int*)(ws + 69210112);
    _Float16* Wqhi = (_Float16*)(ws + 69214208);
    _Float16* Wqlo = (_Float16*)(ws + 71311360);
    _Float16* Wkhi = (_Float16*)(ws + 73408512);
    _Float16* Wklo = (_Float16*)(ws + 75505664);
    _Float16* Wvf  = (_Float16*)(ws + 77602816);
    _Float16* Wof  = (_Float16*)(ws + 79699968);

    _Float16* Vstage = (_Float16*)d_out;
    _Float16* xvf16  = (_Float16*)((char*)d_out + 67108864);

    cvt_split_k<<<dim3(512, 2), 256, 0, stream>>>(Wq, Wqhi, Wqlo, Wk, Wkhi, Wklo, 131072);
    cvt_f16_k<<<dim3(512, 2), 256, 0, stream>>>(Wv, Wvf, Wo, Wof, 131072);
    cvt_f16_k<<<dim3(16384, 1), 256, 0, stream>>>(v, xvf16, v, xvf16, 4194304);

    gemm_v_k<<<dim3(256, 8), 256, 0, stream>>>(xvf16, Wvf, bv, Vstage);

    for (int b = 0; b < Bn; b++) {
        cvt_split_k<<<dim3(2048, 2), 256, 0, stream>>>(
            q + (size_t)b * Ln * Dn, xqhi, xqlo,
            kk + (size_t)b * Ln * Dn, xkhi, xklo, 524288);
        gemm_qk_k<<<dim3(32, 8, 2), 256, 0, stream>>>(
            xqhi, xqlo, xkhi, xklo,
            Wqhi, Wqlo, Wkhi, Wklo, bq, bk,
            Qhi, Qlo, Khi, Klo);
        corr_k<<<dim3(1024), 256, 0, stream>>>(
            Qhi, Qlo, Khi, Klo, corr + (size_t)b * Hn * Ln);
    }
    topk_k<<<128, 256, 0, stream>>>(corr, topw, topi);
    agg_k<<<dim3(64, 128), 256, 0, stream>>>(Vstage, topw, topi, Y);
    gemm_o_k<<<dim3(256, 8), 256, 0, stream>>>(Y, Wof, bo, out);
}

// Round 13
// 2563.060 us; speedup vs baseline: 1.0975x; 1.0975x over previous
//
#include <hip/hip_runtime.h>

#define DEVI static __device__ __forceinline__

typedef float    f32x4 __attribute__((ext_vector_type(4)));
typedef _Float16 f16x8 __attribute__((ext_vector_type(8)));

static constexpr int Bn = 8, Ln = 4096, Dn = 1024, Hn = 16, DKn = 64;
static constexpr int TOPK = 8;
static constexpr float LO_SCALE = 2048.f, LO_INV = 1.f / 2048.f;
static constexpr size_t HLDK = (size_t)Hn * Ln * DKn;   // per-batch Q/K elems

DEVI f32x4 mfma_f16(f16x8 a, f16x8 b, f32x4 c) {
    return __builtin_amdgcn_mfma_f32_16x16x32_f16(a, b, c, 0, 0, 0);
}

struct HL { _Float16 hi, lo; };
// split f32 -> f16 hi + f16 lo*2048 (prescaled so lo stays in normal f16
// range; MFMA flushes subnormal inputs which would kill the correction)
DEVI HL split2(float x) {
    HL r;
    r.hi = (_Float16)x;
    r.lo = (_Float16)((x - (float)r.hi) * LO_SCALE);
    return r;
}

// async global->LDS, 16B per lane, LDS dest = wave-uniform base + lane*16
DEVI void gload16(const void* g, void* l) {
    __builtin_amdgcn_global_load_lds(
        (const __attribute__((address_space(1))) unsigned int*)g,
        (__attribute__((address_space(3))) unsigned int*)l,
        16, 0, 0);
}

// ---------------------------------------------------------------------------
// one-time weight conversion kernels (memory-bound, 4MB each)
// ---------------------------------------------------------------------------
__global__ __launch_bounds__(256) void cvt_split_k(
    const float* __restrict__ srcA, _Float16* __restrict__ hiA, _Float16* __restrict__ loA,
    const float* __restrict__ srcB, _Float16* __restrict__ hiB, _Float16* __restrict__ loB,
    int n8)
{
    const float* s  = blockIdx.y ? srcB : srcA;
    _Float16*    ph = blockIdx.y ? hiB  : hiA;
    _Float16*    pl = blockIdx.y ? loB  : loA;
    const int idx = blockIdx.x * 256 + threadIdx.x;
    if (idx >= n8) return;
    f32x4 x0 = *(const f32x4*)(s + (size_t)idx * 8);
    f32x4 x1 = *(const f32x4*)(s + (size_t)idx * 8 + 4);
    f16x8 h, l;
#pragma unroll
    for (int j = 0; j < 4; j++) {
        HL p0 = split2(x0[j]), p1 = split2(x1[j]);
        h[j] = p0.hi; l[j] = p0.lo;
        h[4 + j] = p1.hi; l[4 + j] = p1.lo;
    }
    *(f16x8*)(ph + (size_t)idx * 8) = h;
    *(f16x8*)(pl + (size_t)idx * 8) = l;
}

__global__ __launch_bounds__(256) void cvt_f16_k(
    const float* __restrict__ srcA, _Float16* __restrict__ dstA,
    const float* __restrict__ srcB, _Float16* __restrict__ dstB, int n8)
{
    const float* s = blockIdx.y ? srcB : srcA;
    _Float16*    d = blockIdx.y ? dstB : dstA;
    const int idx = blockIdx.x * 256 + threadIdx.x;
    if (idx >= n8) return;
    f32x4 x0 = *(const f32x4*)(s + (size_t)idx * 8);
    f32x4 x1 = *(const f32x4*)(s + (size_t)idx * 8 + 4);
    f16x8 o;
#pragma unroll
    for (int j = 0; j < 4; j++) { o[j] = (_Float16)x0[j]; o[4 + j] = (_Float16)x1[j]; }
    *(f16x8*)(d + (size_t)idx * 8) = o;
}

// ---------------------------------------------------------------------------
// m97-structure GEMM: C[m,n] = sum_k A[m,k]*W[n,k] + bias[n], K = 1024.
// 128x128 tile, BK=32, 4 waves, global_load_lds staging, 2-barrier K-loop.
// AF32: A staged as raw f32 (XOR-swizzled source, 16KB tile), cast/split to
//       f16 at fragment load (fuses the cvt pass into the GEMM).
// COMP: x and W in hi + scaled-lo f16; 3-term compensated MFMA (f32-accurate).
// MODE 0: out0 f32 row-major [M][1024]                 (final O-proj)
// MODE 1: out0 f16 head-split [b][h][l][64], b=m>>12   (V staging)
// MODE 2: hi/lo f16 head-split [b2][h][l][64], b2=m>>12 (Q/K, 2 batches)
// ---------------------------------------------------------------------------
DEVI void stage8(const _Float16* gbase, _Float16* ltile, int w, int lane, int k0) {
    // 128x32 f16 tile (8KB) = 8 chunks of 1KB; wave w stages chunks 2w,2w+1
#pragma unroll
    for (int c = 0; c < 2; c++) {
        const int chunk = 2 * w + c;
        const int row = chunk * 16 + (lane >> 2);
        gload16(gbase + (size_t)row * Dn + k0 + (lane & 3) * 8, ltile + chunk * 512);
    }
}

DEVI void stage16f32(const float* gbase, float* ltile, int w, int lane, int k0) {
    // 128x32 f32 tile (16KB) = 16 chunks of 1KB (8 rows each); wave w: 4 chunks.
    // Source col-group pre-swizzled by row (involution g^r) so the LDS image
    // is [row][g] = src[row][g ^ (row&7)] -- read side XORs the same way.
    const int r    = lane >> 3;
    const int gsrc = (lane & 7) ^ r;
#pragma unroll
    for (int c = 0; c < 4; c++) {
        const int chunk = w * 4 + c;
        const int row = chunk * 8 + r;
        gload16(gbase + (size_t)row * Dn + k0 + gsrc * 4, ltile + chunk * 256);
    }
}

template<int MODE, bool COMP, bool AF32>
DEVI void gemm3_body(
    const void* __restrict__ A, const _Float16* __restrict__ W_hi,
    const _Float16* __restrict__ W_lo, const float* __restrict__ bias,
    void* __restrict__ out0, void* __restrict__ out1)
{
    constexpr int ASZ = AF32 ? 16384 : 8192;
    __shared__ char smem[ASZ + (COMP ? 16384 : 8192)];
    float*    sAf = (float*)smem;
    _Float16* sAh = (_Float16*)smem;
    _Float16* sWh = (_Float16*)(smem + ASZ);
    _Float16* sWl = (_Float16*)(smem + ASZ + 8192);

    const int l  = threadIdx.x & 63;
    const int w  = threadIdx.x >> 6;
    const int m0 = blockIdx.x * 128;
    const int n0 = blockIdx.y * 128;
    const int wm = (w & 1) * 64, wn = (w >> 1) * 64;
    const int rr = l & 15, ko = (l >> 4) * 8, g0 = (l >> 4) * 2;

    const _Float16* Wbh = W_hi + (size_t)n0 * Dn;
    const _Float16* Wbl = COMP ? W_lo + (size_t)n0 * Dn : nullptr;

    f32x4 acc[4][4] = {};
    f32x4 accc[4][4] = {};

    for (int k0 = 0; k0 < Dn; k0 += 32) {
        if (AF32) stage16f32((const float*)A + (size_t)m0 * Dn, sAf, w, l, k0);
        else      stage8((const _Float16*)A + (size_t)m0 * Dn, sAh, w, l, k0);
        stage8(Wbh, sWh, w, l, k0);
        if (COMP) stage8(Wbl, sWl, w, l, k0);
        __syncthreads();

        f16x8 af[4], alf[4], bf[4], blf[4];
#pragma unroll
        for (int i = 0; i < 4; i++) {
            const int arow = wm + 16 * i + rr;
            if (AF32) {
                const float* rb = &sAf[arow * 32];
                f32x4 x0 = *(const f32x4*)&rb[((g0    ) ^ (arow & 7)) * 4];
                f32x4 x1 = *(const f32x4*)&rb[((g0 + 1) ^ (arow & 7)) * 4];
#pragma unroll
                for (int j = 0; j < 4; j++) {
                    if (COMP) {
                        HL p0 = split2(x0[j]), p1 = split2(x1[j]);
                        af[i][j] = p0.hi; alf[i][j] = p0.lo;
                        af[i][4 + j] = p1.hi; alf[i][4 + j] = p1.lo;
                    } else {
                        af[i][j]     = (_Float16)x0[j];
                        af[i][4 + j] = (_Float16)x1[j];
                    }
                }
            } else {
                af[i] = *(const f16x8*)&sAh[arow * 32 + ko];
            }
            bf[i] = *(const f16x8*)&sWh[(wn + 16 * i + rr) * 32 + ko];
            if (COMP) blf[i] = *(const f16x8*)&sWl[(wn + 16 * i + rr) * 32 + ko];
        }
#pragma unroll
        for (int i = 0; i < 4; i++)
#pragma unroll
            for (int j = 0; j < 4; j++) {
                acc[i][j] = mfma_f16(af[i], bf[j], acc[i][j]);
                if (COMP) {
                    accc[i][j] = mfma_f16(alf[i], bf[j], accc[i][j]);
                    accc[i][j] = mfma_f16(af[i], blf[j], accc[i][j]);
                }
            }
        __syncthreads();
    }

#pragma unroll
    for (int i = 0; i < 4; i++)
#pragma unroll
        for (int j = 0; j < 4; j++)
#pragma unroll
            for (int r = 0; r < 4; r++) {
                const int m = m0 + wm + 16 * i + (l >> 4) * 4 + r;
                const int n = n0 + wn + 16 * j + (l & 15);
                float v = acc[i][j][r];
                if (COMP) v += accc[i][j][r] * LO_INV;
                v += bias[n];
                if (MODE == 0) {
                    ((float*)out0)[(size_t)m * Dn + n] = v;
                } else {
                    size_t idx = ((size_t)((m >> 12) * Hn + (n >> 6)) * Ln
                                  + (m & (Ln - 1))) * DKn + (n & 63);
                    if (MODE == 1) {
                        ((_Float16*)out0)[idx] = (_Float16)v;
                    } else {
                        HL p = split2(v);
                        ((_Float16*)out0)[idx] = p.hi;
                        ((_Float16*)out1)[idx] = p.lo;
                    }
                }
            }
}

__global__ __launch_bounds__(256) void gemm_v_k(
    const float* __restrict__ xv, const _Float16* __restrict__ Wv,
    const float* __restrict__ bv, _Float16* __restrict__ Vstage)
{
    gemm3_body<1, false, true>(xv, Wv, nullptr, bv, Vstage, nullptr);
}

__global__ __launch_bounds__(256) void gemm_o_k(
    const _Float16* __restrict__ Y, const _Float16* __restrict__ Wo,
    const float* __restrict__ bo, float* __restrict__ out)
{
    gemm3_body<0, false, false>(Y, Wo, nullptr, bo, out, nullptr);
}

// 2 batches per launch (M=8192); z=0 -> Q, z=1 -> K. A = raw f32 input.
__global__ __launch_bounds__(256) void gemm_qk_k(
    const float* __restrict__ xq, const float* __restrict__ xk,
    const _Float16* __restrict__ Wqhi, const _Float16* __restrict__ Wqlo,
    const _Float16* __restrict__ Wkhi, const _Float16* __restrict__ Wklo,
    const float* __restrict__ bq, const float* __restrict__ bk,
    _Float16* __restrict__ Qhi, _Float16* __restrict__ Qlo,
    _Float16* __restrict__ Khi, _Float16* __restrict__ Klo)
{
    if (blockIdx.z == 0)
        gemm3_body<2, true, true>(xq, Wqhi, Wqlo, bq, Qhi, Qlo);
    else
        gemm3_body<2, true, true>(xk, Wkhi, Wklo, bk, Khi, Klo);
}

// ---------------------------------------------------------------------------
// Correlation v7 (REVERTED round-11 version, proven 176us): LDS-staged
// m97-style band kernel. Block = (head h, 64-diag band t0), XCD-swizzled.
// 64 chunks of 64 s-rows; K ring-of-2 + Q staged per chunk; 2-barrier loop.
// XOR-swizzled LDS (source pre-swizzle, read-side XOR).
// ---------------------------------------------------------------------------
__global__ __launch_bounds__(256) void corr_k(
    const _Float16* __restrict__ Qhi, const _Float16* __restrict__ Qlo,
    const _Float16* __restrict__ Khi, const _Float16* __restrict__ Klo,
    float* __restrict__ corr /* [16][4096] of this batch */)
{
    __shared__ _Float16 sK[2][8192];   // [slot][part*4096 + row*64 + col]
    __shared__ _Float16 sQ[8192];
    __shared__ float red[64];

    const int P   = blockIdx.x;
    const int idx = P >> 3;
    const int h   = (P & 7) * 2 + (idx >> 6);   // XCD x hosts heads 2x,2x+1
    const int t0  = (idx & 63) * 64;
    const int l   = threadIdx.x & 63;
    const int w   = threadIdx.x >> 6;
    const int rr  = l & 15;
    const int kf  = (l >> 4) * 8;
    const size_t base = (size_t)h * Ln * DKn;
    const _Float16* Qh = Qhi + base;
    const _Float16* Ql = Qlo + base;
    const _Float16* Kh = Khi + base;
    const _Float16* Kl = Klo + base;

    if (threadIdx.x < 64) red[threadIdx.x] = 0.f;

    // staging lane geometry: each gload16 call covers 8 rows x 64 f16.
    const int lr  = l >> 3;            // row within the 8-row call
    const int gsw = (l & 7) ^ lr;      // pre-swizzled source group (involution)

    f32x4 th[5] = {}, tc[5] = {};

    // prologue: K chunk -1 -> slot 1
    {
#pragma unroll
        for (int cc = 0; cc < 2; cc++) {
            const int Rb = w * 16 + cc * 8;
            const int grow = (-64 - t0 + Rb + lr) & (Ln - 1);
            gload16(Kh + (size_t)grow * DKn + gsw * 8, &sK[1][Rb * 64]);
            gload16(Kl + (size_t)grow * DKn + gsw * 8, &sK[1][4096 + Rb * 64]);
        }
    }

    for (int c = 0; c < 64; c++) {
        // stage K chunk c -> slot c&1, Q chunk c
#pragma unroll
        for (int cc = 0; cc < 2; cc++) {
            const int Rb = w * 16 + cc * 8;
            const int kgrow = (c * 64 - t0 + Rb + lr) & (Ln - 1);
            const int qgrow = c * 64 + Rb + lr;
            gload16(Kh + (size_t)kgrow * DKn + gsw * 8, &sK[c & 1][Rb * 64]);
            gload16(Kl + (size_t)kgrow * DKn + gsw * 8, &sK[c & 1][4096 + Rb * 64]);
            gload16(Qh + (size_t)qgrow * DKn + gsw * 8, &sQ[Rb * 64]);
            gload16(Ql + (size_t)qgrow * DKn + gsw * 8, &sQ[4096 + Rb * 64]);
        }
        __syncthreads();   // drains vmcnt + barrier: all staged data visible

        // Q fragments for si-tile c*4+w (local rows w*16 + rr)
        const int qr = w * 16 + rr;
        const int qsw0 = ((kf >> 3) ^ (qr & 7)) * 8;
        const int qsw1 = (((32 + kf) >> 3) ^ (qr & 7)) * 8;
        f16x8 qh0 = *(const f16x8*)&sQ[qr * 64 + qsw0];
        f16x8 qh1 = *(const f16x8*)&sQ[qr * 64 + qsw1];
        f16x8 ql0 = *(const f16x8*)&sQ[4096 + qr * 64 + qsw0];
        f16x8 ql1 = *(const f16x8*)&sQ[4096 + qr * 64 + qsw1];

#pragma unroll
        for (int j = 0; j <= 4; j++) {
            const int slot = (c + ((w - j) >> 2)) & 1;
            const int kr   = ((w - j) & 3) * 16 + rr;
            const int ksw0 = ((kf >> 3) ^ (kr & 7)) * 8;
            const int ksw1 = (((32 + kf) >> 3) ^ (kr & 7)) * 8;
            f16x8 kh0 = *(const f16x8*)&sK[slot][kr * 64 + ksw0];
            f16x8 kh1 = *(const f16x8*)&sK[slot][kr * 64 + ksw1];
            f16x8 kl0 = *(const f16x8*)&sK[slot][4096 + kr * 64 + ksw0];
            f16x8 kl1 = *(const f16x8*)&sK[slot][4096 + kr * 64 + ksw1];
            th[j] = mfma_f16(qh0, kh0, th[j]);
            th[j] = mfma_f16(qh1, kh1, th[j]);
            tc[j] = mfma_f16(ql0, kh0, tc[j]);
            tc[j] = mfma_f16(qh0, kl0, tc[j]);
            tc[j] = mfma_f16(ql1, kh1, tc[j]);
            tc[j] = mfma_f16(qh1, kl1, tc[j]);
        }
        __syncthreads();   // protect slot (c-1)&1 before re-stage
    }

#pragma unroll
    for (int r = 0; r < 4; r++) {
        const int d  = (l >> 4) * 4 + r - rr;   // a - b
        const int dl = d & 15;
        const bool pos = d >= 0;
#pragma unroll
        for (int i = 0; i < 4; i++) {
            const float hh = pos ? th[i][r] : th[i + 1][r];
            const float cc = pos ? tc[i][r] : tc[i + 1][r];
            atomicAdd(&red[dl + 16 * i], hh + cc * LO_INV);
        }
    }
    __syncthreads();
    if (threadIdx.x < 64)
        corr[(size_t)h * Ln + t0 + threadIdx.x] = red[threadIdx.x];
}

// ---------------------------------------------------------------------------
// Top-8 + softmax per (b,h) row of corr (raw sums; /64 before softmax).
// ---------------------------------------------------------------------------
__global__ __launch_bounds__(256) void topk_k(
    const float* __restrict__ corr, float* __restrict__ top_w,
    int* __restrict__ top_idx)
{
    __shared__ float vals[Ln];
    __shared__ float rv[256];
    __shared__ int   ri[256];
    __shared__ float sel_v[TOPK];
    __shared__ int   sel_i[TOPK];
    const int bh = blockIdx.x;
    const float* c = corr + (size_t)bh * Ln;
    for (int i = threadIdx.x; i < Ln; i += 256) vals[i] = c[i];
    __syncthreads();

    for (int it = 0; it < TOPK; it++) {
        float bvv = -1e30f; int bi = 0;
        const int base = threadIdx.x * 16;
#pragma unroll
        for (int j = 0; j < 16; j++) {
            float v = vals[base + j];
            if (v > bvv) { bvv = v; bi = base + j; }
        }
        rv[threadIdx.x] = bvv; ri[threadIdx.x] = bi;
        __syncthreads();
        if (threadIdx.x == 0) {
            float gv = rv[0]; int gi = ri[0];
            for (int t = 1; t < 256; t++)
                if (rv[t] > gv) { gv = rv[t]; gi = ri[t]; }
            sel_v[it] = gv; sel_i[it] = gi;
            vals[gi] = -1e30f;
        }
        __syncthreads();
    }
    if (threadIdx.x == 0) {
        float e[TOPK], s = 0.f;
        for (int i = 0; i < TOPK; i++) {
            e[i] = expf((sel_v[i] - sel_v[0]) * (1.f / 64.f));
            s += e[i];
        }
        for (int i = 0; i < TOPK; i++) {
            top_w[bh * TOPK + i]   = e[i] / s;
            top_idx[bh * TOPK + i] = sel_i[i];
        }
    }
}

// ---------------------------------------------------------------------------
// Aggregation: Y[b][t][h*64+d] = sum_i w_i * V[b][h][(t-idx_i)&4095][d]
// ---------------------------------------------------------------------------
__global__ __launch_bounds__(256) void agg_k(
    const _Float16* __restrict__ V /* [B][H][L][64] */,
    const float* __restrict__ top_w, const int* __restrict__ top_idx,
    _Float16* __restrict__ Y /* [B][L][1024] */)
{
    __shared__ float w_s[TOPK];
    __shared__ int   i_s[TOPK];
    const int bh   = blockIdx.y;
    const int b    = bh >> 4, h = bh & 15;
    const int tloc = threadIdx.x >> 2;
    const int c16  = (threadIdx.x & 3) * 16;
    const int t    = blockIdx.x * 64 + tloc;
    if (threadIdx.x < TOPK) {
        w_s[threadIdx.x] = top_w[bh * TOPK + threadIdx.x];
        i_s[threadIdx.x] = top_idx[bh * TOPK + threadIdx.x];
    }
    __syncthreads();

    const _Float16* Vb = V + (size_t)bh * Ln * DKn;
    float acc[16] = {};
#pragma unroll
    for (int i = 0; i < TOPK; i++) {
        const int src = (t - i_s[i]) & (Ln - 1);
        const _Float16* p = Vb + (size_t)src * DKn + c16;
        f16x8 v0 = *(const f16x8*)(p);
        f16x8 v1 = *(const f16x8*)(p + 8);
        const float wgt = w_s[i];
#pragma unroll
        for (int j = 0; j < 8; j++) acc[j]     += wgt * (float)v0[j];
#pragma unroll
        for (int j = 0; j < 8; j++) acc[8 + j] += wgt * (float)v1[j];
    }
    f16x8 o0, o1;
#pragma unroll
    for (int j = 0; j < 8; j++) { o0[j] = (_Float16)acc[j]; o1[j] = (_Float16)acc[8 + j]; }
    const size_t oidx = ((size_t)(b * Ln + t)) * Dn + h * DKn + c16;
    *(f16x8*)(Y + oidx)     = o0;
    *(f16x8*)(Y + oidx + 8) = o1;
}

// ---------------------------------------------------------------------------
extern "C" void kernel_launch(void* const* d_in, const int* in_sizes, int n_in,
                              void* d_out, int out_size, void* d_ws, size_t ws_size,
                              hipStream_t stream)
{
    const float* q  = (const float*)d_in[0];
    const float* kk = (const float*)d_in[1];
    const float* v  = (const float*)d_in[2];
    const float* Wq = (const float*)d_in[3];
    const float* bq = (const float*)d_in[4];
    const float* Wk = (const float*)d_in[5];
    const float* bk = (const float*)d_in[6];
    const float* Wv = (const float*)d_in[7];
    const float* bv = (const float*)d_in[8];
    const float* Wo = (const float*)d_in[9];
    const float* bo = (const float*)d_in[10];
    float* out = (float*)d_out;

    // ws layout (bytes):
    //   Qhi2 f16 [2][16][4096][64] @ 0          (16,777,216)   2-batch scratch
    //   Qlo2 @ 16777216
    //   Khi2 @ 33554432
    //   Klo2 @ 50331648                         (end 67,108,864)
    //   Y    f16 [8][4096][1024]   @ 0          (overlays after corr loop)
    //   corr f32 [8][16][4096]     @ 67108864   ( 2,097,152)
    //   topw @ 69206016, topi @ 69210112
    //   Wqhi @ 69214208, Wqlo @ 71311360, Wkhi @ 73408512, Wklo @ 75505664
    //   Wvf  @ 77602816, Wof  @ 79699968       (end 81,797,120)
    char* ws = (char*)d_ws;
    if (ws_size < 81797120ull) return;
    _Float16* Qhi2 = (_Float16*)(ws);
    _Float16* Qlo2 = (_Float16*)(ws + 16777216);
    _Float16* Khi2 = (_Float16*)(ws + 33554432);
    _Float16* Klo2 = (_Float16*)(ws + 50331648);
    _Float16* Y    = (_Float16*)(ws);
    float*    corr = (float*)(ws + 67108864);
    float*    topw = (float*)(ws + 69206016);
    int*      topi = (int*)(ws + 69210112);
    _Float16* Wqhi = (_Float16*)(ws + 69214208);
    _Float16* Wqlo = (_Float16*)(ws + 71311360);
    _Float16* Wkhi = (_Float16*)(ws + 73408512);
    _Float16* Wklo = (_Float16*)(ws + 75505664);
    _Float16* Wvf  = (_Float16*)(ws + 77602816);
    _Float16* Wof  = (_Float16*)(ws + 79699968);

    _Float16* Vstage = (_Float16*)d_out;   // f16 [8][16][4096][64], low half

    // one-time weight conversions (4MB each, cheap)
    cvt_split_k<<<dim3(512, 2), 256, 0, stream>>>(Wq, Wqhi, Wqlo, Wk, Wkhi, Wklo, 131072);
    cvt_f16_k<<<dim3(512, 2), 256, 0, stream>>>(Wv, Wvf, Wo, Wof, 131072);

    // V projection: reads raw f32 v, casts in-kernel (fused cvt).
    gemm_v_k<<<dim3(256, 8), 256, 0, stream>>>(v, Wvf, bv, Vstage);

    for (int p = 0; p < 4; p++) {
        // Q/K projection for batches 2p, 2p+1: raw f32 input, in-kernel split.
        gemm_qk_k<<<dim3(64, 8, 2), 256, 0, stream>>>(
            q + (size_t)p * 2 * Ln * Dn, kk + (size_t)p * 2 * Ln * Dn,
            Wqhi, Wqlo, Wkhi, Wklo, bq, bk,
            Qhi2, Qlo2, Khi2, Klo2);
        for (int bb = 0; bb < 2; bb++) {
            corr_k<<<dim3(1024), 256, 0, stream>>>(
                Qhi2 + bb * HLDK, Qlo2 + bb * HLDK,
                Khi2 + bb * HLDK, Klo2 + bb * HLDK,
                corr + (size_t)(2 * p + bb) * Hn * Ln);
        }
    }
    topk_k<<<128, 256, 0, stream>>>(corr, topw, topi);
    agg_k<<<dim3(64, 128), 256, 0, stream>>>(Vstage, topw, topi, Y);
    gemm_o_k<<<dim3(256, 8), 256, 0, stream>>>(Y, Wof, bo, out);
}

// Round 14
// 1926.259 us; speedup vs baseline: 1.4604x; 1.3306x over previous
//
#include <hip/hip_runtime.h>

#define DEVI static __device__ __forceinline__

typedef float    f32x4 __attribute__((ext_vector_type(4)));
typedef _Float16 f16x8 __attribute__((ext_vector_type(8)));

static constexpr int Bn = 8, Ln = 4096, Dn = 1024, Hn = 16, DKn = 64;
static constexpr int TOPK = 8;
static constexpr float LO_SCALE = 2048.f, LO_INV = 1.f / 2048.f;

DEVI f32x4 mfma_f16(f16x8 a, f16x8 b, f32x4 c) {
    return __builtin_amdgcn_mfma_f32_16x16x32_f16(a, b, c, 0, 0, 0);
}

struct HL { _Float16 hi, lo; };
DEVI HL split2(float x) {
    HL r;
    r.hi = (_Float16)x;
    r.lo = (_Float16)((x - (float)r.hi) * LO_SCALE);
    return r;
}

DEVI void gload16(const void* g, void* l) {
    __builtin_amdgcn_global_load_lds(
        (const __attribute__((address_space(1))) unsigned int*)g,
        (__attribute__((address_space(3))) unsigned int*)l,
        16, 0, 0);
}

// ---------------------------------------------------------------------------
// one-time weight conversion kernels (memory-bound, 4MB each)
// ---------------------------------------------------------------------------
__global__ __launch_bounds__(256) void cvt_split_k(
    const float* __restrict__ srcA, _Float16* __restrict__ hiA, _Float16* __restrict__ loA,
    const float* __restrict__ srcB, _Float16* __restrict__ hiB, _Float16* __restrict__ loB,
    int n8)
{
    const float* s  = blockIdx.y ? srcB : srcA;
    _Float16*    ph = blockIdx.y ? hiB  : hiA;
    _Float16*    pl = blockIdx.y ? loB  : loA;
    const int idx = blockIdx.x * 256 + threadIdx.x;
    if (idx >= n8) return;
    f32x4 x0 = *(const f32x4*)(s + (size_t)idx * 8);
    f32x4 x1 = *(const f32x4*)(s + (size_t)idx * 8 + 4);
    f16x8 h, l;
#pragma unroll
    for (int j = 0; j < 4; j++) {
        HL p0 = split2(x0[j]), p1 = split2(x1[j]);
        h[j] = p0.hi; l[j] = p0.lo;
        h[4 + j] = p1.hi; l[4 + j] = p1.lo;
    }
    *(f16x8*)(ph + (size_t)idx * 8) = h;
    *(f16x8*)(pl + (size_t)idx * 8) = l;
}

__global__ __launch_bounds__(256) void cvt_f16_k(
    const float* __restrict__ srcA, _Float16* __restrict__ dstA,
    const float* __restrict__ srcB, _Float16* __restrict__ dstB, int n8)
{
    const float* s = blockIdx.y ? srcB : srcA;
    _Float16*    d = blockIdx.y ? dstB : dstA;
    const int idx = blockIdx.x * 256 + threadIdx.x;
    if (idx >= n8) return;
    f32x4 x0 = *(const f32x4*)(s + (size_t)idx * 8);
    f32x4 x1 = *(const f32x4*)(s + (size_t)idx * 8 + 4);
    f16x8 o;
#pragma unroll
    for (int j = 0; j < 4; j++) { o[j] = (_Float16)x0[j]; o[4 + j] = (_Float16)x1[j]; }
    *(f16x8*)(d + (size_t)idx * 8) = o;
}

// ---------------------------------------------------------------------------
// m97-structure GEMM (unchanged core from round 13).
// MODE 0: out0 f32 row-major [M][1024]                  (final O-proj)
// MODE 1: out0 f16 head-split [b][h][l][64], b=m>>12    (V staging)
// MODE 2: out0 f32 TRANSPOSED [b2][n][l] (n=h*64+d)     (Q/K for FFT corr)
// ---------------------------------------------------------------------------
DEVI void stage8(const _Float16* gbase, _Float16* ltile, int w, int lane, int k0) {
#pragma unroll
    for (int c = 0; c < 2; c++) {
        const int chunk = 2 * w + c;
        const int row = chunk * 16 + (lane >> 2);
        gload16(gbase + (size_t)row * Dn + k0 + (lane & 3) * 8, ltile + chunk * 512);
    }
}

DEVI void stage16f32(const float* gbase, float* ltile, int w, int lane, int k0) {
    const int r    = lane >> 3;
    const int gsrc = (lane & 7) ^ r;
#pragma unroll
    for (int c = 0; c < 4; c++) {
        const int chunk = w * 4 + c;
        const int row = chunk * 8 + r;
        gload16(gbase + (size_t)row * Dn + k0 + gsrc * 4, ltile + chunk * 256);
    }
}

template<int MODE, bool COMP, bool AF32>
DEVI void gemm3_body(
    const void* __restrict__ A, const _Float16* __restrict__ W_hi,
    const _Float16* __restrict__ W_lo, const float* __restrict__ bias,
    void* __restrict__ out0)
{
    constexpr int ASZ = AF32 ? 16384 : 8192;
    __shared__ char smem[ASZ + (COMP ? 16384 : 8192)];
    float*    sAf = (float*)smem;
    _Float16* sAh = (_Float16*)smem;
    _Float16* sWh = (_Float16*)(smem + ASZ);
    _Float16* sWl = (_Float16*)(smem + ASZ + 8192);

    const int l  = threadIdx.x & 63;
    const int w  = threadIdx.x >> 6;
    const int m0 = blockIdx.x * 128;
    const int n0 = blockIdx.y * 128;
    const int wm = (w & 1) * 64, wn = (w >> 1) * 64;
    const int rr = l & 15, ko = (l >> 4) * 8, g0 = (l >> 4) * 2;

    const _Float16* Wbh = W_hi + (size_t)n0 * Dn;
    const _Float16* Wbl = COMP ? W_lo + (size_t)n0 * Dn : nullptr;

    f32x4 acc[4][4] = {};
    f32x4 accc[4][4] = {};

    for (int k0 = 0; k0 < Dn; k0 += 32) {
        if (AF32) stage16f32((const float*)A + (size_t)m0 * Dn, sAf, w, l, k0);
        else      stage8((const _Float16*)A + (size_t)m0 * Dn, sAh, w, l, k0);
        stage8(Wbh, sWh, w, l, k0);
        if (COMP) stage8(Wbl, sWl, w, l, k0);
        __syncthreads();

        f16x8 af[4], alf[4], bf[4], blf[4];
#pragma unroll
        for (int i = 0; i < 4; i++) {
            const int arow = wm + 16 * i + rr;
            if (AF32) {
                const float* rb = &sAf[arow * 32];
                f32x4 x0 = *(const f32x4*)&rb[((g0    ) ^ (arow & 7)) * 4];
                f32x4 x1 = *(const f32x4*)&rb[((g0 + 1) ^ (arow & 7)) * 4];
#pragma unroll
                for (int j = 0; j < 4; j++) {
                    if (COMP) {
                        HL p0 = split2(x0[j]), p1 = split2(x1[j]);
                        af[i][j] = p0.hi; alf[i][j] = p0.lo;
                        af[i][4 + j] = p1.hi; alf[i][4 + j] = p1.lo;
                    } else {
                        af[i][j]     = (_Float16)x0[j];
                        af[i][4 + j] = (_Float16)x1[j];
                    }
                }
            } else {
                af[i] = *(const f16x8*)&sAh[arow * 32 + ko];
            }
            bf[i] = *(const f16x8*)&sWh[(wn + 16 * i + rr) * 32 + ko];
            if (COMP) blf[i] = *(const f16x8*)&sWl[(wn + 16 * i + rr) * 32 + ko];
        }
#pragma unroll
        for (int i = 0; i < 4; i++)
#pragma unroll
            for (int j = 0; j < 4; j++) {
                acc[i][j] = mfma_f16(af[i], bf[j], acc[i][j]);
                if (COMP) {
                    accc[i][j] = mfma_f16(alf[i], bf[j], accc[i][j]);
                    accc[i][j] = mfma_f16(af[i], blf[j], accc[i][j]);
                }
            }
        __syncthreads();
    }

#pragma unroll
    for (int i = 0; i < 4; i++)
#pragma unroll
        for (int j = 0; j < 4; j++)
#pragma unroll
            for (int r = 0; r < 4; r++) {
                const int m = m0 + wm + 16 * i + (l >> 4) * 4 + r;
                const int n = n0 + wn + 16 * j + (l & 15);
                float v = acc[i][j][r];
                if (COMP) v += accc[i][j][r] * LO_INV;
                v += bias[n];
                if (MODE == 0) {
                    ((float*)out0)[(size_t)m * Dn + n] = v;
                } else if (MODE == 1) {
                    size_t idx = ((size_t)((m >> 12) * Hn + (n >> 6)) * Ln
                                  + (m & (Ln - 1))) * DKn + (n & 63);
                    ((_Float16*)out0)[idx] = (_Float16)v;
                } else {
                    // transposed f32: [b2][n][l]; quads of lanes -> 64B runs
                    size_t idx = (((size_t)(m >> 12) << 10) + n) * Ln + (m & (Ln - 1));
                    ((float*)out0)[idx] = v;
                }
            }
}

__global__ __launch_bounds__(256) void gemm_v_k(
    const float* __restrict__ xv, const _Float16* __restrict__ Wv,
    const float* __restrict__ bv, _Float16* __restrict__ Vstage)
{
    gemm3_body<1, false, true>(xv, Wv, nullptr, bv, Vstage);
}

__global__ __launch_bounds__(256) void gemm_o_k(
    const _Float16* __restrict__ Y, const _Float16* __restrict__ Wo,
    const float* __restrict__ bo, float* __restrict__ out)
{
    gemm3_body<0, false, false>(Y, Wo, nullptr, bo, out);
}

// 2 batches per launch (M=8192); z=0 -> Q, z=1 -> K. A = raw f32 input.
__global__ __launch_bounds__(256) void gemm_qk_k(
    const float* __restrict__ xq, const float* __restrict__ xk,
    const _Float16* __restrict__ Wqhi, const _Float16* __restrict__ Wqlo,
    const _Float16* __restrict__ Wkhi, const _Float16* __restrict__ Wklo,
    const float* __restrict__ bq, const float* __restrict__ bk,
    float* __restrict__ QT, float* __restrict__ KT)
{
    if (blockIdx.z == 0)
        gemm3_body<2, true, true>(xq, Wqhi, Wqlo, bq, QT);
    else
        gemm3_body<2, true, true>(xk, Wkhi, Wklo, bk, KT);
}

// ---------------------------------------------------------------------------
// FFT-based correlation.
// corr[bh][t] = Sum_d IFFT( FFT(Q_col_d) * conj(FFT(K_col_d)) )[t]
// Forward radix-4 Stockham FFT, N=4096, 6 passes, LDS ping-pong, 256 thr.
// Verified formulation (Govindaraju): stage Ns=4^s, p=j%Ns,
//   twiddle w^r = exp(-2pi*i*r*p/(4Ns)), radix-4 DFT, dst=(j/Ns)*4Ns+p+r*Ns.
// Inverse via conj trick: IFFT(P) = conj(FFT(conj(P)))/N.
// ---------------------------------------------------------------------------
DEVI int FPAD(int i) { return i + (i >> 4); }   // +1 float2 per 16 (bank pad)

DEVI float2 cmulf(float2 a, float2 b) {
    return make_float2(a.x * b.x - a.y * b.y, a.x * b.y + a.y * b.x);
}

DEVI void fft_pass(const float2* in, float2* out, int ls2, int tid) {
    const int Ns = 1 << ls2;
#pragma unroll
    for (int r = 0; r < 4; r++) {
        const int j = tid + r * 256;          // 0..1023
        float2 v0 = in[FPAD(j)];
        float2 v1 = in[FPAD(j + 1024)];
        float2 v2 = in[FPAD(j + 2048)];
        float2 v3 = in[FPAD(j + 3072)];
        const int p = j & (Ns - 1);
        const float ang = -6.283185307179586f * (float)p / (4.f * (float)Ns);
        float sn, cs;
        __sincosf(ang, &sn, &cs);
        const float2 w1 = make_float2(cs, sn);
        const float2 w2 = cmulf(w1, w1);
        const float2 w3 = cmulf(w2, w1);
        v1 = cmulf(v1, w1); v2 = cmulf(v2, w2); v3 = cmulf(v3, w3);
        const float2 t0 = make_float2(v0.x + v2.x, v0.y + v2.y);
        const float2 t1 = make_float2(v0.x - v2.x, v0.y - v2.y);
        const float2 t2 = make_float2(v1.x + v3.x, v1.y + v3.y);
        const float2 t3 = make_float2(v1.x - v3.x, v1.y - v3.y);
        const float2 t3i = make_float2(t3.y, -t3.x);   // -i * t3
        const int db = ((j >> ls2) << (ls2 + 2)) | p;
        out[FPAD(db)]          = make_float2(t0.x + t2.x, t0.y + t2.y);
        out[FPAD(db + Ns)]     = make_float2(t1.x + t3i.x, t1.y + t3i.y);
        out[FPAD(db + 2 * Ns)] = make_float2(t0.x - t2.x, t0.y - t2.y);
        out[FPAD(db + 3 * Ns)] = make_float2(t1.x - t3i.x, t1.y - t3i.y);
    }
}

DEVI void fft4096(float2* A, float2* B, int tid) {
    __syncthreads();
    fft_pass(A, B, 0, tid);  __syncthreads();
    fft_pass(B, A, 2, tid);  __syncthreads();
    fft_pass(A, B, 4, tid);  __syncthreads();
    fft_pass(B, A, 6, tid);  __syncthreads();
    fft_pass(A, B, 8, tid);  __syncthreads();
    fft_pass(B, A, 10, tid); __syncthreads();
    // result in A (natural order)
}

// grid (16 d-quads, 32 bh); Pf = this pair's [32][4096] complex accumulator
__global__ __launch_bounds__(256) void fftcorr_k(
    const float* __restrict__ QT, const float* __restrict__ KT,
    float2* __restrict__ Pf)
{
    __shared__ float2 A[4352], B[4352];
    const int tid = threadIdx.x;
    const int bh  = blockIdx.y;
    const int d0  = blockIdx.x * 4;
    float2 acc[16];
#pragma unroll
    for (int i = 0; i < 16; i++) acc[i] = make_float2(0.f, 0.f);
    float2 qf[16];

    for (int dd = 0; dd < 4; dd++) {
        const int d = d0 + dd;
        const float* qc = QT + ((size_t)bh * 64 + d) * Ln;
        const float* kc = KT + ((size_t)bh * 64 + d) * Ln;
#pragma unroll
        for (int i = 0; i < 16; i++) {
            const int row = tid + 256 * i;
            A[FPAD(row)] = make_float2(qc[row], 0.f);
        }
        fft4096(A, B, tid);
#pragma unroll
        for (int i = 0; i < 16; i++) qf[i] = A[FPAD(tid + 256 * i)];
        __syncthreads();
#pragma unroll
        for (int i = 0; i < 16; i++) {
            const int row = tid + 256 * i;
            A[FPAD(row)] = make_float2(kc[row], 0.f);
        }
        fft4096(A, B, tid);
#pragma unroll
        for (int i = 0; i < 16; i++) {
            float2 kf = A[FPAD(tid + 256 * i)];
            acc[i].x += qf[i].x * kf.x + qf[i].y * kf.y;   // qf * conj(kf)
            acc[i].y += qf[i].y * kf.x - qf[i].x * kf.y;
        }
        __syncthreads();
    }
    float2* P = Pf + (size_t)bh * Ln;
#pragma unroll
    for (int i = 0; i < 16; i++) {
        atomicAdd(&P[tid + 256 * i].x, acc[i].x);
        atomicAdd(&P[tid + 256 * i].y, acc[i].y);
    }
}

// grid 128 blocks: corr[bh][t] = Re(FFT(conj(Pf[bh])))[t] / 4096
__global__ __launch_bounds__(256) void ifftcorr_k(
    const float2* __restrict__ Pf, float* __restrict__ corr)
{
    __shared__ float2 A[4352], B[4352];
    const int tid = threadIdx.x;
    const int bh = blockIdx.x;
    const float2* P = Pf + (size_t)bh * Ln;
#pragma unroll
    for (int i = 0; i < 16; i++) {
        float2 v = P[tid + 256 * i];
        A[FPAD(tid + 256 * i)] = make_float2(v.x, -v.y);
    }
    fft4096(A, B, tid);
#pragma unroll
    for (int i = 0; i < 16; i++)
        corr[(size_t)bh * Ln + tid + 256 * i] =
            A[FPAD(tid + 256 * i)].x * (1.f / 4096.f);
}

// ---------------------------------------------------------------------------
// Top-8 + softmax per (b,h) row of corr (raw sums; /64 before softmax).
// ---------------------------------------------------------------------------
__global__ __launch_bounds__(256) void topk_k(
    const float* __restrict__ corr, float* __restrict__ top_w,
    int* __restrict__ top_idx)
{
    __shared__ float vals[Ln];
    __shared__ float rv[256];
    __shared__ int   ri[256];
    __shared__ float sel_v[TOPK];
    __shared__ int   sel_i[TOPK];
    const int bh = blockIdx.x;
    const float* c = corr + (size_t)bh * Ln;
    for (int i = threadIdx.x; i < Ln; i += 256) vals[i] = c[i];
    __syncthreads();

    for (int it = 0; it < TOPK; it++) {
        float bvv = -1e30f; int bi = 0;
        const int base = threadIdx.x * 16;
#pragma unroll
        for (int j = 0; j < 16; j++) {
            float v = vals[base + j];
            if (v > bvv) { bvv = v; bi = base + j; }
        }
        rv[threadIdx.x] = bvv; ri[threadIdx.x] = bi;
        __syncthreads();
        if (threadIdx.x == 0) {
            float gv = rv[0]; int gi = ri[0];
            for (int t = 1; t < 256; t++)
                if (rv[t] > gv) { gv = rv[t]; gi = ri[t]; }
            sel_v[it] = gv; sel_i[it] = gi;
            vals[gi] = -1e30f;
        }
        __syncthreads();
    }
    if (threadIdx.x == 0) {
        float e[TOPK], s = 0.f;
        for (int i = 0; i < TOPK; i++) {
            e[i] = expf((sel_v[i] - sel_v[0]) * (1.f / 64.f));
            s += e[i];
        }
        for (int i = 0; i < TOPK; i++) {
            top_w[bh * TOPK + i]   = e[i] / s;
            top_idx[bh * TOPK + i] = sel_i[i];
        }
    }
}

// ---------------------------------------------------------------------------
// Aggregation: Y[b][t][h*64+d] = sum_i w_i * V[b][h][(t-idx_i)&4095][d]
// ---------------------------------------------------------------------------
__global__ __launch_bounds__(256) void agg_k(
    const _Float16* __restrict__ V /* [B][H][L][64] */,
    const float* __restrict__ top_w, const int* __restrict__ top_idx,
    _Float16* __restrict__ Y /* [B][L][1024] */)
{
    __shared__ float w_s[TOPK];
    __shared__ int   i_s[TOPK];
    const int bh   = blockIdx.y;
    const int b    = bh >> 4, h = bh & 15;
    const int tloc = threadIdx.x >> 2;
    const int c16  = (threadIdx.x & 3) * 16;
    const int t    = blockIdx.x * 64 + tloc;
    if (threadIdx.x < TOPK) {
        w_s[threadIdx.x] = top_w[bh * TOPK + threadIdx.x];
        i_s[threadIdx.x] = top_idx[bh * TOPK + threadIdx.x];
    }
    __syncthreads();

    const _Float16* Vb = V + (size_t)bh * Ln * DKn;
    float acc[16] = {};
#pragma unroll
    for (int i = 0; i < TOPK; i++) {
        const int src = (t - i_s[i]) & (Ln - 1);
        const _Float16* p = Vb + (size_t)src * DKn + c16;
        f16x8 v0 = *(const f16x8*)(p);
        f16x8 v1 = *(const f16x8*)(p + 8);
        const float wgt = w_s[i];
#pragma unroll
        for (int j = 0; j < 8; j++) acc[j]     += wgt * (float)v0[j];
#pragma unroll
        for (int j = 0; j < 8; j++) acc[8 + j] += wgt * (float)v1[j];
    }
    f16x8 o0, o1;
#pragma unroll
    for (int j = 0; j < 8; j++) { o0[j] = (_Float16)acc[j]; o1[j] = (_Float16)acc[8 + j]; }
    const size_t oidx = ((size_t)(b * Ln + t)) * Dn + h * DKn + c16;
    *(f16x8*)(Y + oidx)     = o0;
    *(f16x8*)(Y + oidx + 8) = o1;
}

// ---------------------------------------------------------------------------
extern "C" void kernel_launch(void* const* d_in, const int* in_sizes, int n_in,
                              void* d_out, int out_size, void* d_ws, size_t ws_size,
                              hipStream_t stream)
{
    const float* q  = (const float*)d_in[0];
    const float* kk = (const float*)d_in[1];
    const float* v  = (const float*)d_in[2];
    const float* Wq = (const float*)d_in[3];
    const float* bq = (const float*)d_in[4];
    const float* Wk = (const float*)d_in[5];
    const float* bk = (const float*)d_in[6];
    const float* Wv = (const float*)d_in[7];
    const float* bv = (const float*)d_in[8];
    const float* Wo = (const float*)d_in[9];
    const float* bo = (const float*)d_in[10];
    float* out = (float*)d_out;

    // ws layout (bytes):
    //   QT   f32 [2][1024][4096] @ 0         (33,554,432)  per 2-batch pair
    //   KT   f32 [2][1024][4096] @ 33554432  (33,554,432)
    //   Y    f16 [8][4096][1024] @ 0         (overlays after FFT loop)
    //   corr f32 [8][16][4096]   @ 67108864  ( 2,097,152)
    //   topw @ 69206016, topi @ 69210112
    //   Wqhi @ 69214208, Wqlo @ 71311360, Wkhi @ 73408512, Wklo @ 75505664
    //   Wvf  @ 77602816, Wof  @ 79699968
    //   Pf   cf32 [128][4096]    @ 81797120  ( 4,194,304)  (end 85,991,424)
    char* ws = (char*)d_ws;
    if (ws_size < 85991424ull) return;
    float*    QT   = (float*)(ws);
    float*    KT   = (float*)(ws + 33554432);
    _Float16* Y    = (_Float16*)(ws);
    float*    corr = (float*)(ws + 67108864);
    float*    topw = (float*)(ws + 69206016);
    int*      topi = (int*)(ws + 69210112);
    _Float16* Wqhi = (_Float16*)(ws + 69214208);
    _Float16* Wqlo = (_Float16*)(ws + 71311360);
    _Float16* Wkhi = (_Float16*)(ws + 73408512);
    _Float16* Wklo = (_Float16*)(ws + 75505664);
    _Float16* Wvf  = (_Float16*)(ws + 77602816);
    _Float16* Wof  = (_Float16*)(ws + 79699968);
    float2*   Pf   = (float2*)(ws + 81797120);

    _Float16* Vstage = (_Float16*)d_out;   // f16 [8][16][4096][64], low half

    (void)hipMemsetAsync(Pf, 0, (size_t)128 * Ln * sizeof(float2), stream);

    cvt_split_k<<<dim3(512, 2), 256, 0, stream>>>(Wq, Wqhi, Wqlo, Wk, Wkhi, Wklo, 131072);
    cvt_f16_k<<<dim3(512, 2), 256, 0, stream>>>(Wv, Wvf, Wo, Wof, 131072);

    gemm_v_k<<<dim3(256, 8), 256, 0, stream>>>(v, Wvf, bv, Vstage);

    for (int p = 0; p < 4; p++) {
        gemm_qk_k<<<dim3(64, 8, 2), 256, 0, stream>>>(
            q + (size_t)p * 2 * Ln * Dn, kk + (size_t)p * 2 * Ln * Dn,
            Wqhi, Wqlo, Wkhi, Wklo, bq, bk, QT, KT);
        fftcorr_k<<<dim3(16, 32), 256, 0, stream>>>(QT, KT, Pf + (size_t)p * 32 * Ln);
    }
    ifftcorr_k<<<128, 256, 0, stream>>>(Pf, corr);
    topk_k<<<128, 256, 0, stream>>>(corr, topw, topi);
    agg_k<<<dim3(64, 128), 256, 0, stream>>>(Vstage, topw, topi, Y);
    gemm_o_k<<<dim3(256, 8), 256, 0, stream>>>(Y, Wof, bo, out);
}